// Round 15
// baseline (569.721 us; speedup 1.0000x reference)
//
#include <hip/hip_runtime.h>
#include <hip/hip_bf16.h>
#include <math.h>

#define NB 32
#define NNODE 64
#define DD 128
#define NSQ 4096
#define EDGES 16384
#define LAYERS 6

typedef __bf16 bf16x8 __attribute__((ext_vector_type(8)));
typedef float f32x4 __attribute__((ext_vector_type(4)));

typedef __attribute__((address_space(1))) const unsigned int g_u32;
typedef __attribute__((address_space(3))) unsigned int l_u32;
__device__ __forceinline__ void gll16(const void* g, void* l){
  __builtin_amdgcn_global_load_lds((g_u32*)g, (l_u32*)l, 16, 0, 0);
}

__device__ __forceinline__ float silu_f(float x){ return x / (1.f + __expf(-x)); }
__device__ __forceinline__ float bf2f(unsigned short h){
  union{unsigned int u; float f;} x; x.u = ((unsigned int)h)<<16; return x.f;
}
// add two packs of 8 bf16 in f32, round back to bf16
__device__ __forceinline__ uint4 addbf8(uint4 a, uint4 b){
  union { __bf16 h[8]; uint4 u; } A, B, O;
  A.u = a; B.u = b;
  #pragma unroll
  for (int e=0;e<8;e++) O.h[e] = (__bf16)((float)A.h[e] + (float)B.h[e]);
  return O.u;
}

// ---------------- time embedding ----------------
__global__ void k_temb(const float* __restrict__ t, const float* __restrict__ W1,
                       const float* __restrict__ b1, const float* __restrict__ W2,
                       const float* __restrict__ b2, float* __restrict__ tt){
  int b = blockIdx.x, d = threadIdx.x;
  __shared__ float h[DD];
  float v = t[b]*W1[d] + b1[d];
  h[d] = silu_f(v);
  __syncthreads();
  float acc = b2[d];
  #pragma unroll 4
  for (int k=0;k<DD;k++) acc = fmaf(h[k], W2[k*DD+d], acc);
  tt[b*DD+d] = silu_f(acc);
}

// ---------------- edge-type table (16 types) ----------------
__global__ void k_edgeenc(const float* __restrict__ emb, const float* __restrict__ W1,
                          const float* __restrict__ b1, const float* __restrict__ W2,
                          const float* __restrict__ b2, float* __restrict__ enc){
  int et = blockIdx.x, tid = threadIdx.x;
  __shared__ float e0[DD];
  __shared__ float hid[2*DD];
  if (tid < DD) e0[tid] = emb[et*DD + tid];
  __syncthreads();
  float a = b1[tid];
  for (int d2=0; d2<DD; d2++) a = fmaf(e0[d2], W1[d2*256 + tid], a);
  hid[tid] = fmaxf(a, 0.f);
  __syncthreads();
  if (tid < DD){
    float o = b2[tid];
    for (int k=0;k<256;k++) o = fmaf(hid[k], W2[k*DD + tid], o);
    enc[et*DD + tid] = o;
  }
}

// ---------------- histogram scatter: 1 atomic per edge ----------------
__global__ void k_cnt(const int* __restrict__ ei, const int* __restrict__ attr,
                      unsigned int* __restrict__ cnt, int b0){
  int e = b0*512 + blockIdx.x*256 + threadIdx.x;
  int s = ei[e], dN = ei[EDGES+e];
  int g = (s>>6) - b0, u = s&63, v = dN&63;
  atomicAdd(&cnt[((size_t)g*4096 + v*64 + u)*16 + attr[e]], 1u);
}

// ---------------- expand ----------------
__global__ __launch_bounds__(256) void k_expand(const unsigned int* __restrict__ cnt,
    const float* __restrict__ enc, const float* __restrict__ tt,
    __bf16* __restrict__ A_S, int b0){
  __shared__ float encs[16][128];
  __shared__ float ttl[128];
  __shared__ __bf16 tb[8][256];
  int g = blockIdx.x >> 4;
  int cell0 = (blockIdx.x & 15) << 8;
  int tid = threadIdx.x;
  for (int s = tid; s < 2048; s += 256) encs[s>>7][s&127] = enc[s];
  if (tid < 128) ttl[tid] = tt[(b0+g)*128 + tid];
  unsigned int c16[16];
  { const uint4* src = (const uint4*)(cnt + ((size_t)g*4096 + cell0 + tid)*16);
    uint4 a = src[0], b = src[1], c = src[2], d = src[3];
    c16[0]=a.x; c16[1]=a.y; c16[2]=a.z; c16[3]=a.w;
    c16[4]=b.x; c16[5]=b.y; c16[6]=b.z; c16[7]=b.w;
    c16[8]=c.x; c16[9]=c.y; c16[10]=c.z; c16[11]=c.w;
    c16[12]=d.x; c16[13]=d.y; c16[14]=d.z; c16[15]=d.w; }
  __syncthreads();
  for (int dc=0; dc<16; dc++){
    int d0 = dc*8;
    float vals[8] = {0.f,0.f,0.f,0.f,0.f,0.f,0.f,0.f};
    #pragma unroll
    for (int et=0; et<16; et++){
      unsigned int c = c16[et];
      if (c){
        float fc = (float)c;
        #pragma unroll
        for (int dd=0; dd<8; dd++) vals[dd] = fmaf(fc, encs[et][d0+dd], vals[dd]);
      }
    }
    #pragma unroll
    for (int dd=0; dd<8; dd++) tb[dd][tid] = (__bf16)(vals[dd]*ttl[d0+dd]);
    __syncthreads();
    { int dd = tid>>5, seg = tid&31;
      uint4 v = *(const uint4*)&tb[dd][seg*8];
      *(uint4*)(A_S + ((size_t)(g*128 + d0 + dd)<<12) + cell0 + seg*8) = v; }
    __syncthreads();
  }
}

// ---------------- weight prep: Wt[fo][K] = W^T in bf16 ----------------
__global__ __launch_bounds__(256) void k_wprep(const float* __restrict__ W1, const float* __restrict__ W2,
                                               const float* __restrict__ Wm, __bf16* __restrict__ WT){
  int b = blockIdx.x, t = threadIdx.x;
  const float* src; __bf16* dst; int K;
  if (b < 6){ src = W1 + (size_t)b*384*128; dst = WT + (size_t)b*49152; K = 384; }
  else if (b < 12){ src = W2 + (size_t)(b-6)*128*128; dst = WT + 294912 + (size_t)(b-6)*16384; K = 128; }
  else { src = Wm; dst = WT + 393216; K = 128; }
  __shared__ float L[64][129];
  for (int k0 = 0; k0 < K; k0 += 64){
    __syncthreads();
    int r = t>>2, c = (t&3)*32;
    #pragma unroll
    for (int e=0;e<32;e+=4){
      float4 x = *(const float4*)(src + (size_t)(k0+r)*128 + c + e);
      L[r][c+e]=x.x; L[r][c+e+1]=x.y; L[r][c+e+2]=x.z; L[r][c+e+3]=x.w;
    }
    __syncthreads();
    int fo = t>>1, kk = (t&1)*32;
    union { __bf16 h[32]; uint4 u[4]; } o;
    #pragma unroll
    for (int e=0;e<32;e++) o.h[e] = (__bf16)L[kk+e][fo];
    uint4* d4 = (uint4*)(dst + (size_t)fo*K + k0 + kk);
    d4[0]=o.u[0]; d4[1]=o.u[1]; d4[2]=o.u[2]; d4[3]=o.u[3];
  }
}

// ---------------- fn weight prep ----------------
__global__ __launch_bounds__(256) void k_wprepfn(const float* __restrict__ W1, const float* __restrict__ W2,
                                                 __bf16* __restrict__ o1, __bf16* __restrict__ o2){
  int b = blockIdx.x, t = threadIdx.x;
  const float* src; __bf16* dst; int K, N, k0, n0;
  if (b < 8){ src = W1; dst = o1; K = 128; N = 256; k0 = (b>>2)*64; n0 = (b&3)*64; }
  else { int bb = b-8; src = W2; dst = o2; K = 256; N = 128; k0 = (bb>>1)*64; n0 = (bb&1)*64; }
  __shared__ float L[64][65];
  int r = t>>2, c4 = (t&3)*16;
  #pragma unroll
  for (int e=0;e<16;e+=4){
    float4 x = *(const float4*)(src + (size_t)(k0+r)*N + n0 + c4 + e);
    L[r][c4+e]=x.x; L[r][c4+e+1]=x.y; L[r][c4+e+2]=x.z; L[r][c4+e+3]=x.w;
  }
  __syncthreads();
  int n = t>>2, kc = (t&3)*16;
  union { __bf16 h[16]; uint4 u[2]; } o;
  #pragma unroll
  for (int e=0;e<16;e++) o.h[e] = (__bf16)L[kc+e][n];
  uint4* d4 = (uint4*)(dst + (size_t)(n0+n)*K + k0 + kc);
  d4[0]=o.u[0]; d4[1]=o.u[1];
}

// ---------------- einsum (MFMA): GLL staging; derives transposes; coalesced C-write ----------------
__global__ __launch_bounds__(256) void k_einsum(const __bf16* __restrict__ As,
                                                const __bf16* __restrict__ Xs,
                                                __bf16* __restrict__ X1t, __bf16* __restrict__ X2t){
  __shared__ __bf16 S[8][4096];
  int tid = threadIdx.x;
  int w = tid>>6, lane = tid&63;
  size_t p0 = (size_t)blockIdx.x * 2;
  {
    int slot = (w<2) ? (2+w) : (4+w);
    const __bf16* srcp = ((w<2) ? As : Xs) + (p0 + (w&1))*4096;
    #pragma unroll
    for (int c8 = 0; c8 < 8; c8++){
      int row = c8*8 + (lane>>3);
      int ch  = (lane&7) ^ (row&7);
      gll16(srcp + row*64 + ch*8, (char*)&S[slot][0] + c8*1024);
    }
  }
  __syncthreads();
  {
    int q = tid>>6, v = tid&63;
    int ssl = (q<2) ? (2+q) : (4+q);
    int dsl = (q<2) ? q : (2+q);
    const unsigned char* sb = (const unsigned char*)S[ssl];
    unsigned char* db = (unsigned char*)S[dsl];
    #pragma unroll
    for (int uo=0; uo<8; uo++){
      union { __bf16 h[8]; uint4 u; } pk;
      #pragma unroll
      for (int e=0;e<8;e++){
        int u = uo*8+e;
        pk.h[e] = *(const __bf16*)(sb + u*128 + (((v>>3) ^ (u&7))<<4) + (v&7)*2);
      }
      *(uint4*)(db + v*128 + ((uo ^ (v&7))<<4)) = pk.u;
    }
  }
  __syncthreads();
  int pl = w>>1, pr = w&1;
  const __bf16* M  = pr ? S[4+pl] : S[0+pl];
  const __bf16* Bt = pr ? S[2+pl] : S[6+pl];
  f32x4 acc[4][4];
  #pragma unroll
  for (int a=0;a<4;a++)
    #pragma unroll
    for(int b=0;b<4;b++) acc[a][b] = (f32x4){0.f,0.f,0.f,0.f};
  int lr = lane&15, lq = lane>>4;
  #pragma unroll
  for (int ks=0;ks<2;ks++){
    bf16x8 af[4], bfr[4];
    #pragma unroll
    for (int mt=0;mt<4;mt++){ int r = mt*16+lr; af[mt] = *(const bf16x8*)&M[r*64 + (((ks*4+lq) ^ (r&7))<<3)]; }
    #pragma unroll
    for (int nt=0;nt<4;nt++){ int r = nt*16+lr; bfr[nt] = *(const bf16x8*)&Bt[r*64 + (((ks*4+lq) ^ (r&7))<<3)]; }
    #pragma unroll
    for (int mt=0;mt<4;mt++)
      #pragma unroll
      for (int nt=0;nt<4;nt++)
        acc[mt][nt] = __builtin_amdgcn_mfma_f32_16x16x32_bf16(af[mt], bfr[nt], acc[mt][nt], 0,0,0);
  }
  {
    int dslot = pr ? (4+pl) : pl;
    unsigned char* db = (unsigned char*)&S[dslot][0];
    #pragma unroll
    for (int mt=0;mt<4;mt++)
      #pragma unroll
      for (int nt=0;nt<4;nt++){
        int col = nt*16 + lr; int row0 = mt*16 + lq*4;
        union { __bf16 h[4]; uint2 u; } o;
        #pragma unroll
        for (int r=0;r<4;r++) o.h[r] = (__bf16)acc[mt][nt][r];
        int chunk = row0>>3;
        *(uint2*)(db + col*128 + ((chunk ^ (col&7))<<4) + (row0&7)*2) = o.u;
      }
  }
  __syncthreads();
  #pragma unroll
  for (int s4=0; s4<4; s4++){
    int slot = (s4<2) ? s4 : (2+s4);
    __bf16* dst = ((s4<2) ? X1t : X2t) + (p0 + (s4&1))*4096;
    const unsigned char* sb = (const unsigned char*)&S[slot][0];
    #pragma unroll
    for (int q=0;q<2;q++){
      int t2 = tid + q*256;
      int col = t2>>3, rc = t2&7;
      uint4 v = *(const uint4*)(sb + col*128 + ((rc ^ (col&7))<<4));
      *(uint4*)(dst + t2*8) = v;
    }
  }
}

// ---------------- fused conv1+LN1+relu+conv2+LN2+relu+residual ----------------
// 3-stage pipeline, ONE barrier per K-step; setprio(1) around MFMA clusters (T5).
__global__ __launch_bounds__(256) void k_layer(const __bf16* __restrict__ Xold,
    const __bf16* __restrict__ X1, const __bf16* __restrict__ X2,
    const __bf16* __restrict__ W1t, const __bf16* __restrict__ W2t,
    const float* __restrict__ b1v, const float* __restrict__ g1v, const float* __restrict__ bt1v,
    const float* __restrict__ b2v, const float* __restrict__ g2v, const float* __restrict__ bt2v,
    __bf16* __restrict__ Xnew){
  __shared__ __align__(16) unsigned char RG[32768];
  __shared__ float stats[2][128];
  __bf16* y1T = (__bf16*)RG;
  float (*redS)[128] = (float(*)[128])(RG + 16384);
  float (*redQ)[128] = (float(*)[128])(RG + 18432);
  int tid = threadIdx.x, w = tid>>6, lane = tid&63, lr = lane&15, lq = lane>>4;
  int colTile = blockIdx.x << 7;
  int bl = colTile >> 12;
  int colInB = colTile & 4095;
  int s_fi = tid>>3, s_o = tid&7;
  int r_col = tid>>1;

  f32x4 acc[2][8];
  #pragma unroll
  for (int a=0;a<2;a++)
    #pragma unroll
    for (int b=0;b<8;b++) acc[a][b] = (f32x4){0.f,0.f,0.f,0.f};

#define STAGE(ks, nb) { \
    int gfi = (ks)*32 + s_fi; \
    const __bf16* T = (gfi<128)? Xold : (gfi<256? X1 : X2); \
    int d = gfi & 127; \
    const uint4* src = (const uint4*)(T + ((size_t)(bl*128 + d)<<12) + colInB + s_o*16); \
    uint4 v0 = src[0], v1 = src[1]; \
    unsigned char* Nd = RG + (nb)*8192; \
    *(uint4*)(Nd + s_fi*256 + (((s_o*2+0) ^ (s_fi&15))<<4)) = v0; \
    *(uint4*)(Nd + s_fi*256 + (((s_o*2+1) ^ (s_fi&15))<<4)) = v1; \
  }

#define REPACK(nb) { \
    const unsigned char* Ns = RG + (nb)*8192; \
    unsigned char* Cd = RG + 16384 + (nb)*8192; \
    _Pragma("unroll") \
    for (int j=0;j<2;j++){ \
      int oct = (tid&1)*2 + j; \
      union { __bf16 h[8]; uint4 u; } pk; \
      _Pragma("unroll") \
      for (int e=0;e<8;e++){ \
        int fi = oct*8 + e; \
        pk.h[e] = *(const __bf16*)(Ns + fi*256 + (((r_col>>3) ^ (fi&15))<<4) + (r_col&7)*2); \
      } \
      *(uint4*)(Cd + r_col*64 + ((oct ^ (r_col&3))<<4)) = pk.u; \
    } \
  }

  STAGE(0, 0)
  STAGE(1, 1)
  __syncthreads();
  REPACK(0)
  __syncthreads();

  for (int k=0; k<11; k++){
    int cb = k&1, nb = cb^1;
    const unsigned char* Cc = RG + 16384 + cb*8192;
    bf16x8 af[2];
    #pragma unroll
    for (int mt=0;mt<2;mt++){
      int fo = w*32 + mt*16 + lr;
      af[mt] = *(const bf16x8*)(W1t + (size_t)fo*384 + k*32 + lq*8);
    }
    bf16x8 bfr[8];
    #pragma unroll
    for (int nt=0;nt<8;nt++){ int cr = nt*16+lr; bfr[nt] = *(const bf16x8*)(Cc + cr*64 + ((lq ^ (cr&3))<<4)); }
    __builtin_amdgcn_s_setprio(1);
    #pragma unroll
    for (int mt=0;mt<2;mt++)
      #pragma unroll
      for (int nt=0;nt<8;nt++)
        acc[mt][nt] = __builtin_amdgcn_mfma_f32_16x16x32_bf16(af[mt], bfr[nt], acc[mt][nt], 0,0,0);
    __builtin_amdgcn_s_setprio(0);
    REPACK(nb)
    if (k < 10) STAGE(k+2, cb)
    __syncthreads();
  }
  {
    const unsigned char* Cc = RG + 16384 + 8192;
    bf16x8 af[2];
    #pragma unroll
    for (int mt=0;mt<2;mt++){
      int fo = w*32 + mt*16 + lr;
      af[mt] = *(const bf16x8*)(W1t + (size_t)fo*384 + 11*32 + lq*8);
    }
    bf16x8 bfr[8];
    #pragma unroll
    for (int nt=0;nt<8;nt++){ int cr = nt*16+lr; bfr[nt] = *(const bf16x8*)(Cc + cr*64 + ((lq ^ (cr&3))<<4)); }
    __builtin_amdgcn_s_setprio(1);
    #pragma unroll
    for (int mt=0;mt<2;mt++)
      #pragma unroll
      for (int nt=0;nt<8;nt++)
        acc[mt][nt] = __builtin_amdgcn_mfma_f32_16x16x32_bf16(af[mt], bfr[nt], acc[mt][nt], 0,0,0);
    __builtin_amdgcn_s_setprio(0);
  }

  #pragma unroll
  for (int mt=0;mt<2;mt++){
    #pragma unroll
    for (int r=0;r<4;r++){
      float bv = b1v[w*32 + mt*16 + lq*4 + r];
      #pragma unroll
      for (int nt=0;nt<8;nt++) acc[mt][nt][r] += bv;
    }
  }
  {
    float cs[8], cq[8];
    #pragma unroll
    for (int nt=0;nt<8;nt++){ cs[nt]=0.f; cq[nt]=0.f; }
    #pragma unroll
    for (int mt=0;mt<2;mt++)
      #pragma unroll
      for (int nt=0;nt<8;nt++)
        #pragma unroll
        for (int r=0;r<4;r++){ float v = acc[mt][nt][r]; cs[nt] += v; cq[nt] = fmaf(v,v,cq[nt]); }
    #pragma unroll
    for (int nt=0;nt<8;nt++){
      cs[nt] += __shfl_xor(cs[nt], 16); cq[nt] += __shfl_xor(cq[nt], 16);
      cs[nt] += __shfl_xor(cs[nt], 32); cq[nt] += __shfl_xor(cq[nt], 32);
    }
    if (lq == 0){
      #pragma unroll
      for (int nt=0;nt<8;nt++){ redS[w][nt*16+lr] = cs[nt]; redQ[w][nt*16+lr] = cq[nt]; }
    }
  }
  __syncthreads();
  if (tid < 128){
    float S = redS[0][tid]+redS[1][tid]+redS[2][tid]+redS[3][tid];
    float Q = redQ[0][tid]+redQ[1][tid]+redQ[2][tid]+redQ[3][tid];
    float m = S*(1.f/128.f);
    float var = Q*(1.f/128.f) - m*m;
    stats[0][tid] = m; stats[1][tid] = rsqrtf(var + 1e-5f);
  }
  __syncthreads();
  #pragma unroll
  for (int mt=0;mt<2;mt++){
    int fo1b = w*32 + mt*16 + lq*4;
    float ga[4], be[4];
    #pragma unroll
    for (int r=0;r<4;r++){ ga[r] = g1v[fo1b+r]; be[r] = bt1v[fo1b+r]; }
    #pragma unroll
    for (int nt=0;nt<8;nt++){
      int col = nt*16 + lr;
      union { __bf16 h[4]; uint2 u; } o;
      #pragma unroll
      for (int r=0;r<4;r++){
        float xx = (acc[mt][nt][r] - stats[0][col]) * stats[1][col] * ga[r] + be[r];
        o.h[r] = (__bf16)fmaxf(xx, 0.f);
      }
      *(uint2*)&y1T[col*128 + (fo1b ^ ((col&15)<<3))] = o.u;
    }
  }
  __syncthreads();

  f32x4 acc2[2][8];
  #pragma unroll
  for (int a=0;a<2;a++)
    #pragma unroll
    for (int b=0;b<8;b++) acc2[a][b] = (f32x4){0.f,0.f,0.f,0.f};
  #pragma unroll
  for (int ks2=0; ks2<4; ks2++){
    bf16x8 af[2], bfr[8];
    #pragma unroll
    for (int mt=0;mt<2;mt++){
      int fo = w*32 + mt*16 + lr;
      af[mt] = *(const bf16x8*)(W2t + (size_t)fo*128 + ks2*32 + lq*8);
    }
    #pragma unroll
    for (int nt=0;nt<8;nt++){ int cr = nt*16+lr; bfr[nt] = *(const bf16x8*)&y1T[cr*128 + ((ks2*32 + lq*8) ^ ((cr&15)<<3))]; }
    __builtin_amdgcn_s_setprio(1);
    #pragma unroll
    for (int mt=0;mt<2;mt++)
      #pragma unroll
      for (int nt=0;nt<8;nt++)
        acc2[mt][nt] = __builtin_amdgcn_mfma_f32_16x16x32_bf16(af[mt], bfr[nt], acc2[mt][nt], 0,0,0);
    __builtin_amdgcn_s_setprio(0);
  }
  __syncthreads();

  #pragma unroll
  for (int mt=0;mt<2;mt++){
    #pragma unroll
    for (int r=0;r<4;r++){
      float bv = b2v[w*32 + mt*16 + lq*4 + r];
      #pragma unroll
      for (int nt=0;nt<8;nt++) acc2[mt][nt][r] += bv;
    }
  }
  {
    float cs[8], cq[8];
    #pragma unroll
    for (int nt=0;nt<8;nt++){ cs[nt]=0.f; cq[nt]=0.f; }
    #pragma unroll
    for (int mt=0;mt<2;mt++)
      #pragma unroll
      for (int nt=0;nt<8;nt++)
        #pragma unroll
        for (int r=0;r<4;r++){ float v = acc2[mt][nt][r]; cs[nt] += v; cq[nt] = fmaf(v,v,cq[nt]); }
    #pragma unroll
    for (int nt=0;nt<8;nt++){
      cs[nt] += __shfl_xor(cs[nt], 16); cq[nt] += __shfl_xor(cq[nt], 16);
      cs[nt] += __shfl_xor(cs[nt], 32); cq[nt] += __shfl_xor(cq[nt], 32);
    }
    if (lq == 0){
      #pragma unroll
      for (int nt=0;nt<8;nt++){ redS[w][nt*16+lr] = cs[nt]; redQ[w][nt*16+lr] = cq[nt]; }
    }
  }
  __syncthreads();
  if (tid < 128){
    float S = redS[0][tid]+redS[1][tid]+redS[2][tid]+redS[3][tid];
    float Q = redQ[0][tid]+redQ[1][tid]+redQ[2][tid]+redQ[3][tid];
    float m = S*(1.f/128.f);
    float var = Q*(1.f/128.f) - m*m;
    stats[0][tid] = m; stats[1][tid] = rsqrtf(var + 1e-5f);
  }
  __syncthreads();
  #pragma unroll
  for (int mt=0;mt<2;mt++){
    #pragma unroll
    for (int r=0;r<4;r++){
      int fo = w*32 + mt*16 + lq*4 + r;
      float ga = g2v[fo], be = bt2v[fo];
      size_t rowb = ((size_t)(bl*128 + fo)<<12) + colInB;
      #pragma unroll
      for (int nt=0;nt<8;nt++){
        int cp = nt*16 + lr;
        float xx = (acc2[mt][nt][r] - stats[0][cp]) * stats[1][cp] * ga + be;
        float o = fmaxf(xx, 0.f);
        float old = (float)Xold[rowb + cp];
        Xnew[rowb + cp] = (__bf16)(o + old);
      }
    }
  }
#undef STAGE
#undef REPACK
}

// ---------------- to node-major (unsymmetrized): NM0[g*4096+cell][d] = X_S[g*128+d][cell] ----------------
__global__ __launch_bounds__(256) void k_tonm(const __bf16* __restrict__ S, __bf16* __restrict__ NM){
  __shared__ unsigned short L[64][65];
  int b = blockIdx.x;
  int g = b >> 7, dh = (b>>6)&1, cc = b&63;
  int cell0 = cc*64, d0 = dh*64;
  int tid = threadIdx.x;
  int r = tid>>2, c = (tid&3)*16;
  union { unsigned short h[16]; uint4 u[2]; } in;
  const unsigned short* src = (const unsigned short*)S + ((size_t)(g*128 + d0 + r)<<12) + cell0 + c;
  in.u[0] = *(const uint4*)src;
  in.u[1] = *(const uint4*)(src + 8);
  #pragma unroll
  for (int e=0;e<16;e++) L[r][c+e] = in.h[e];
  __syncthreads();
  union { unsigned short h[16]; uint4 u[2]; } o;
  int cr = tid>>2, dc = (tid&3)*16;
  #pragma unroll
  for (int e=0;e<16;e++) o.h[e] = L[dc+e][cr];
  unsigned short* dst = (unsigned short*)NM + (size_t)(g*4096 + cell0 + cr)*128 + d0 + dc;
  *(uint4*)dst       = o.u[0];
  *(uint4*)(dst + 8) = o.u[1];
}

// ---------------- mlp hidden from cell-major; symmetrize on the fly (row + rowT) ----------------
__global__ __launch_bounds__(256) void k_mlph(const __bf16* __restrict__ NM,
    const __bf16* __restrict__ Wt, const float* __restrict__ bias, __bf16* __restrict__ hid){
  __shared__ __align__(16) unsigned char WcB[8192];
  __shared__ __align__(16) unsigned char EcB[8192];
  __bf16* Wc = (__bf16*)WcB;
  unsigned char* Ec = EcB;
  int tid = threadIdx.x, w = tid>>6, lane = tid&63, lr = lane&15, lq = lane>>4;
  int g = blockIdx.x >> 5;
  int cellloc0 = (blockIdx.x & 31) << 7;
  size_t cellbase = ((size_t)g<<12) + cellloc0;
  int mh = w&1, nh = w>>1;
  f32x4 acc[4][4];
  #pragma unroll
  for (int a=0;a<4;a++)
    #pragma unroll
    for (int b=0;b<4;b++) acc[a][b] = (f32x4){0.f,0.f,0.f,0.f};
  for (int ks=0; ks<4; ks++){
    __syncthreads();
    { int fo = tid>>1, half = tid&1;
      const uint4* src = (const uint4*)(Wt + (size_t)fo*128 + ks*32 + half*16);
      uint4 v0 = src[0], v1 = src[1];
      *(uint4*)&Wc[fo*32 + (((half*2+0) ^ (fo&3))<<3)] = v0;
      *(uint4*)&Wc[fo*32 + (((half*2+1) ^ (fo&3))<<3)] = v1;
    }
    { int cell = tid>>1, half = tid&1;
      int cl = cellloc0 + cell;            // local cell in batch
      int v = cl>>6, u = cl&63;
      size_t cT = ((size_t)g<<12) + u*64 + v;   // transposed cell
      const uint4* src  = (const uint4*)(NM + (cellbase + cell)*128 + ks*32 + half*16);
      const uint4* srcT = (const uint4*)(NM + cT*128 + ks*32 + half*16);
      uint4 v0 = addbf8(src[0], srcT[0]);
      uint4 v1 = addbf8(src[1], srcT[1]);
      *(uint4*)(Ec + cell*64 + (((half*2+0) ^ (cell&3))<<4)) = v0;
      *(uint4*)(Ec + cell*64 + (((half*2+1) ^ (cell&3))<<4)) = v1;
    }
    __syncthreads();
    bf16x8 af[4], bfr[4];
    #pragma unroll
    for (int mt=0;mt<4;mt++){ int cr = mh*64 + mt*16 + lr; af[mt] = *(const bf16x8*)(Ec + cr*64 + ((lq ^ (cr&3))<<4)); }
    #pragma unroll
    for (int nt=0;nt<4;nt++){ int fo = nh*64 + nt*16 + lr; bfr[nt] = *(const bf16x8*)&Wc[fo*32 + ((lq ^ (fo&3))<<3)]; }
    #pragma unroll
    for (int mt=0;mt<4;mt++)
      #pragma unroll
      for (int nt=0;nt<4;nt++)
        acc[mt][nt] = __builtin_amdgcn_mfma_f32_16x16x32_bf16(af[mt], bfr[nt], acc[mt][nt], 0,0,0);
  }
  #pragma unroll
  for (int mt=0;mt<4;mt++)
    #pragma unroll
    for (int r=0;r<4;r++){
      size_t cell = cellbase + mh*64 + mt*16 + lq*4 + r;
      #pragma unroll
      for (int nt=0;nt<4;nt++){
        int fo = nh*64 + nt*16 + lr;
        hid[cell*128 + fo] = (__bf16)silu_f(acc[mt][nt][r] + bias[fo]);
      }
    }
}

// ---------------- ym ----------------
__global__ void k_ymean(const __bf16* __restrict__ hid, float* __restrict__ ym){
  __shared__ float red[256];
  int g = blockIdx.x >> 6, u = blockIdx.x & 63;
  int fo = threadIdx.x & 127, vh = threadIdx.x >> 7;
  const unsigned short* hu = (const unsigned short*)hid;
  float s = 0.f;
  for (int v = vh; v < 64; v += 2)
    s += bf2f(hu[((size_t)g*4096 + v*64 + u)*128 + fo]);
  red[threadIdx.x] = s;
  __syncthreads();
  if (vh == 0) ym[((size_t)g*64 + u)*128 + fo] = (red[fo] + red[128+fo]) * (1.f/64.f);
}

// ---------------- h2 ----------------
__global__ void k_h2(const float* __restrict__ ym, const float* __restrict__ W2,
                     const float* __restrict__ b2, float* __restrict__ h2){
  int row = blockIdx.x, fo = threadIdx.x;
  __shared__ float rr[128];
  rr[fo] = ym[(size_t)row*128 + fo];
  __syncthreads();
  float a = b2[fo];
  #pragma unroll 4
  for (int k=0;k<128;k++) a = fmaf(rr[k], W2[k*128+fo], a);
  h2[(size_t)row*128+fo] = a;
}

// ---------------- final MLP (MFMA); GATHER path symmetrizes (cell + cellT) ----------------
template<int GATHER>
__global__ __launch_bounds__(256) void k_fmlp(const __bf16* __restrict__ NM, const float* __restrict__ RWS,
    const int* __restrict__ ei,
    const __bf16* __restrict__ W1t, const float* __restrict__ b1,
    const __bf16* __restrict__ W2t, const float* __restrict__ b2,
    float* __restrict__ outp, int b0){
  __shared__ __align__(16) unsigned char RA[32768];
  __shared__ __align__(16) unsigned char RB[8192];
  __shared__ int cells[64];
  __shared__ int cellsT[64];
  __bf16* eo  = (__bf16*)RA;
  __bf16* Wc  = (__bf16*)(RA + 16384);
  __bf16* hid = (__bf16*)RA;
  __bf16* W2c = (__bf16*)RB;
  int tid = threadIdx.x, w = tid>>6, lane = tid&63, lr = lane&15, lq = lane>>4;
  int r0 = blockIdx.x*64;
  if (GATHER){
    if (tid < 64){
      int e = b0*512 + r0 + tid;
      int s = ei[e], dN = ei[EDGES+e];
      int g = (s>>6) - b0, u = s&63, v = dN&63;
      cells[tid]  = g*4096 + v*64 + u;
      cellsT[tid] = g*4096 + u*64 + v;
    }
    __syncthreads();
  }
  { int el = tid>>2, o4 = tid&3;
    if (GATHER){
      const unsigned short* src  = (const unsigned short*)NM + (size_t)cells[el]*128;
      const unsigned short* srcT = (const unsigned short*)NM + (size_t)cellsT[el]*128;
      #pragma unroll
      for (int j=0;j<4;j++){
        int ch = o4*4 + j;
        uint4 v = addbf8(*(const uint4*)(src + ch*8), *(const uint4*)(srcT + ch*8));
        *(uint4*)&eo[el*128 + ((ch*8) ^ ((el&15)*8))] = v;
      }
    } else {
      const float* src = RWS + (size_t)(r0 + el)*128;
      #pragma unroll
      for (int j=0;j<4;j++){
        int ch = o4*4 + j;
        union { __bf16 h[8]; uint4 u; } pk;
        #pragma unroll
        for (int e2=0;e2<8;e2++) pk.h[e2] = (__bf16)src[ch*8 + e2];
        *(uint4*)&eo[el*128 + ((ch*8) ^ ((el&15)*8))] = pk.u;
      }
    }
  }
  f32x4 acc[4][4];
  #pragma unroll
  for (int a=0;a<4;a++)
    #pragma unroll
    for (int b=0;b<4;b++) acc[a][b] = (f32x4){0.f,0.f,0.f,0.f};
  for (int ks=0; ks<4; ks++){
    if (ks) __syncthreads();
    { int fo = tid;
      const uint4* src = (const uint4*)(W1t + (size_t)fo*128 + ks*32);
      #pragma unroll
      for (int o=0;o<4;o++){
        uint4 v = src[o];
        *(uint4*)&Wc[fo*32 + ((o ^ (fo&3))<<3)] = v;
      }
    }
    __syncthreads();
    bf16x8 af[4], bfr[4];
    #pragma unroll
    for (int mt=0;mt<4;mt++){ int fo = w*64+mt*16+lr; af[mt] = *(const bf16x8*)&Wc[fo*32 + ((lq ^ (fo&3))<<3)]; }
    #pragma unroll
    for (int nt=0;nt<4;nt++){ int ed = nt*16+lr; bfr[nt] = *(const bf16x8*)&eo[ed*128 + ((ks*32+lq*8) ^ ((ed&15)*8))]; }
    #pragma unroll
    for (int mt=0;mt<4;mt++)
      #pragma unroll
      for (int nt=0;nt<4;nt++)
        acc[mt][nt] = __builtin_amdgcn_mfma_f32_16x16x32_bf16(af[mt], bfr[nt], acc[mt][nt], 0,0,0);
  }
  __syncthreads();
  #pragma unroll
  for (int mt=0;mt<4;mt++){
    int fob = w*64 + mt*16 + lq*4;
    float bv[4];
    #pragma unroll
    for (int r=0;r<4;r++) bv[r] = b1[fob+r];
    #pragma unroll
    for (int nt=0;nt<4;nt++){
      int ed = nt*16 + lr;
      union { __bf16 h[4]; uint2 u; } o;
      #pragma unroll
      for (int r=0;r<4;r++) o.h[r] = (__bf16)fmaxf(acc[mt][nt][r] + bv[r], 0.f);
      *(uint2*)&hid[ed*256 + (fob ^ ((ed&31)*8))] = o.u;
    }
  }
  f32x4 acc2[4][2];
  #pragma unroll
  for (int a=0;a<4;a++)
    #pragma unroll
    for (int b=0;b<2;b++) acc2[a][b] = (f32x4){0.f,0.f,0.f,0.f};
  int mh = w&1, nh = w>>1;
  for (int ks2=0; ks2<8; ks2++){
    __syncthreads();
    { int fo = tid>>1, half = tid&1;
      const uint4* src = (const uint4*)(W2t + (size_t)fo*256 + ks2*32 + half*16);
      uint4 v0 = src[0], v1 = src[1];
      *(uint4*)&W2c[fo*32 + (((half*2+0) ^ (fo&3))<<3)] = v0;
      *(uint4*)&W2c[fo*32 + (((half*2+1) ^ (fo&3))<<3)] = v1;
    }
    __syncthreads();
    bf16x8 af2[4], bfr2[2];
    #pragma unroll
    for (int mt=0;mt<4;mt++){ int fo2 = mh*64+mt*16+lr; af2[mt] = *(const bf16x8*)&W2c[fo2*32 + ((lq ^ (fo2&3))<<3)]; }
    #pragma unroll
    for (int nt=0;nt<2;nt++){ int ed = nh*32+nt*16+lr; bfr2[nt] = *(const bf16x8*)&hid[ed*256 + ((ks2*32+lq*8) ^ ((ed&31)*8))]; }
    #pragma unroll
    for (int mt=0;mt<4;mt++)
      #pragma unroll
      for (int nt=0;nt<2;nt++)
        acc2[mt][nt] = __builtin_amdgcn_mfma_f32_16x16x32_bf16(af2[mt], bfr2[nt], acc2[mt][nt], 0,0,0);
  }
  #pragma unroll
  for (int mt=0;mt<4;mt++){
    int fo2b = mh*64 + mt*16 + lq*4;
    float bv[4];
    #pragma unroll
    for (int r=0;r<4;r++) bv[r] = b2[fo2b+r];
    #pragma unroll
    for (int nt=0;nt<2;nt++){
      int ed = nh*32 + nt*16 + lr;
      float4 o = make_float4(acc2[mt][nt][0]+bv[0], acc2[mt][nt][1]+bv[1],
                             acc2[mt][nt][2]+bv[2], acc2[mt][nt][3]+bv[3]);
      *(float4*)(outp + (size_t)(r0 + ed)*128 + fo2b) = o;
    }
  }
}

// ---------------- graph_attr ----------------
__global__ void k_graph(const float* __restrict__ node_out, float* __restrict__ gout){
  int b = blockIdx.x, d = threadIdx.x;
  float s = 0.f;
  for (int i=0;i<64;i++) s += node_out[(size_t)(b*64+i)*128 + d];
  gout[b*128 + d] = s * (1.f/64.f);
}

extern "C" void kernel_launch(void* const* d_in, const int* in_sizes, int n_in,
                              void* d_out, int out_size, void* d_ws, size_t ws_size,
                              hipStream_t stream) {
  const int*   edge_index = (const int*)d_in[1];
  const int*   edge_attr  = (const int*)d_in[2];
  const float* t        = (const float*)d_in[3];
  const float* edge_emb = (const float*)d_in[5];
  const float* temb_W1  = (const float*)d_in[6];
  const float* temb_b1  = (const float*)d_in[7];
  const float* temb_W2  = (const float*)d_in[8];
  const float* temb_b2  = (const float*)d_in[9];
  const float* ein_W1   = (const float*)d_in[14];
  const float* ein_b1   = (const float*)d_in[15];
  const float* ein_W2   = (const float*)d_in[16];
  const float* ein_b2   = (const float*)d_in[17];
  const float* conv_W1  = (const float*)d_in[18];
  const float* conv_b1  = (const float*)d_in[19];
  const float* conv_g1  = (const float*)d_in[20];
  const float* conv_bt1 = (const float*)d_in[21];
  const float* conv_W2  = (const float*)d_in[22];
  const float* conv_b2  = (const float*)d_in[23];
  const float* conv_g2  = (const float*)d_in[24];
  const float* conv_bt2 = (const float*)d_in[25];
  const float* mlp_W1   = (const float*)d_in[26];
  const float* mlp_b1   = (const float*)d_in[27];
  const float* mlp_W2   = (const float*)d_in[28];
  const float* mlp_b2   = (const float*)d_in[29];
  const float* fn_W1    = (const float*)d_in[30];
  const float* fn_b1    = (const float*)d_in[31];
  const float* fn_W2    = (const float*)d_in[32];
  const float* fn_b2    = (const float*)d_in[33];

  float* ws  = (float*)d_ws;
  float* tt  = ws;
  float* enc = ws + 4096;
  float* ym  = ws + 6144;
  float* h2  = ws + 268288;
  __bf16* WT = (__bf16*)(ws + 530432);
  unsigned int* cnt = (unsigned int*)(ws + 768000);
  const size_t HDRF = 2883584;

  __bf16* fnW1t = WT + 409600;
  __bf16* fnW2t = WT + 442368;

  size_t availF = ws_size / sizeof(float);
  const int cands[6] = {32, 16, 8, 4, 2, 1};
  int C = 1;
  for (int i = 0; i < 6; i++){
    if (HDRF + 4ull * (size_t)cands[i] * 262144ull <= availF){ C = cands[i]; break; }
  }
  const size_t PCB = (size_t)C * 262144;
  __bf16* A_S = (__bf16*)(ws + HDRF);
  __bf16* X_S = (__bf16*)(ws + HDRF + PCB);
  __bf16* X1  = (__bf16*)(ws + HDRF + 2*PCB);
  __bf16* X2  = (__bf16*)(ws + HDRF + 3*PCB);
  float* outf = (float*)d_out;

  k_temb<<<NB, DD, 0, stream>>>(t, temb_W1, temb_b1, temb_W2, temb_b2, tt);
  k_edgeenc<<<16, 256, 0, stream>>>(edge_emb, ein_W1, ein_b1, ein_W2, ein_b2, enc);
  k_wprep<<<13, 256, 0, stream>>>(conv_W1, conv_W2, mlp_W1, WT);
  k_wprepfn<<<16, 256, 0, stream>>>(fn_W1, fn_W2, fnW1t, fnW2t);

  for (int b0 = 0; b0 < NB; b0 += C){
    hipMemsetAsync(cnt, 0, (size_t)C*4096*16*sizeof(unsigned int), stream);
    k_cnt<<<C*2, 256, 0, stream>>>(edge_index, edge_attr, cnt, b0);
    k_expand<<<C*16, 256, 0, stream>>>(cnt, enc, tt, A_S, b0);

    for (int l=0; l<LAYERS; l++){
      const __bf16* Xs_l = (l==0) ? A_S : X_S;
      k_einsum<<<C*64, 256, 0, stream>>>(A_S, Xs_l, X1, X2);
      k_layer<<<C*32, 256, 0, stream>>>(Xs_l, X1, X2,
          WT + (size_t)l*49152, WT + 294912 + (size_t)l*16384,
          conv_b1 + l*DD, conv_g1 + l*DD, conv_bt1 + l*DD,
          conv_b2 + l*DD, conv_g2 + l*DD, conv_bt2 + l*DD, X_S);
    }

    k_tonm<<<C*128, 256, 0, stream>>>(X_S, X1);           // X1 = NM0 (unsymmetrized cell-major)
    k_mlph<<<C*32, 256, 0, stream>>>(X1, WT + 393216, mlp_b1, X2);  // sym on the fly
    k_ymean<<<C*64, 256, 0, stream>>>(X2, ym);
    k_h2<<<C*64, 128, 0, stream>>>(ym, mlp_W2, mlp_b2, h2);
    k_fmlp<1><<<C*8, 256, 0, stream>>>(X1, nullptr, edge_index, fnW1t, fn_b1, fnW2t, fn_b2,
                                       outf + 262144 + (size_t)b0*512*128, b0);
    k_fmlp<0><<<C, 256, 0, stream>>>(nullptr, h2, nullptr, fnW1t, fn_b1, fnW2t, fn_b2,
                                     outf + (size_t)b0*64*128, b0);
    k_graph<<<C, DD, 0, stream>>>(outf + (size_t)b0*64*DD, outf + 2359296 + b0*DD);
  }
}

// Round 16
// 550.147 us; speedup vs baseline: 1.0356x; 1.0356x over previous
//
#include <hip/hip_runtime.h>
#include <hip/hip_bf16.h>
#include <math.h>

#define NB 32
#define NNODE 64
#define DD 128
#define NSQ 4096
#define EDGES 16384
#define LAYERS 6

typedef __bf16 bf16x8 __attribute__((ext_vector_type(8)));
typedef float f32x4 __attribute__((ext_vector_type(4)));

typedef __attribute__((address_space(1))) const unsigned int g_u32;
typedef __attribute__((address_space(3))) unsigned int l_u32;
__device__ __forceinline__ void gll16(const void* g, void* l){
  __builtin_amdgcn_global_load_lds((g_u32*)g, (l_u32*)l, 16, 0, 0);
}

__device__ __forceinline__ float silu_f(float x){ return x / (1.f + __expf(-x)); }
__device__ __forceinline__ float bf2f(unsigned short h){
  union{unsigned int u; float f;} x; x.u = ((unsigned int)h)<<16; return x.f;
}
__device__ __forceinline__ uint4 addbf8(uint4 a, uint4 b){
  union { __bf16 h[8]; uint4 u; } A, B, O;
  A.u = a; B.u = b;
  #pragma unroll
  for (int e=0;e<8;e++) O.h[e] = (__bf16)((float)A.h[e] + (float)B.h[e]);
  return O.u;
}

// ---------------- time embedding ----------------
__global__ void k_temb(const float* __restrict__ t, const float* __restrict__ W1,
                       const float* __restrict__ b1, const float* __restrict__ W2,
                       const float* __restrict__ b2, float* __restrict__ tt){
  int b = blockIdx.x, d = threadIdx.x;
  __shared__ float h[DD];
  float v = t[b]*W1[d] + b1[d];
  h[d] = silu_f(v);
  __syncthreads();
  float acc = b2[d];
  #pragma unroll 4
  for (int k=0;k<DD;k++) acc = fmaf(h[k], W2[k*DD+d], acc);
  tt[b*DD+d] = silu_f(acc);
}

// ---------------- edge-type table (16 types) ----------------
__global__ void k_edgeenc(const float* __restrict__ emb, const float* __restrict__ W1,
                          const float* __restrict__ b1, const float* __restrict__ W2,
                          const float* __restrict__ b2, float* __restrict__ enc){
  int et = blockIdx.x, tid = threadIdx.x;
  __shared__ float e0[DD];
  __shared__ float hid[2*DD];
  if (tid < DD) e0[tid] = emb[et*DD + tid];
  __syncthreads();
  float a = b1[tid];
  for (int d2=0; d2<DD; d2++) a = fmaf(e0[d2], W1[d2*256 + tid], a);
  hid[tid] = fmaxf(a, 0.f);
  __syncthreads();
  if (tid < DD){
    float o = b2[tid];
    for (int k=0;k<256;k++) o = fmaf(hid[k], W2[k*DD + tid], o);
    enc[et*DD + tid] = o;
  }
}

// ---------------- histogram scatter: 1 atomic per edge ----------------
__global__ void k_cnt(const int* __restrict__ ei, const int* __restrict__ attr,
                      unsigned int* __restrict__ cnt, int b0){
  int e = b0*512 + blockIdx.x*256 + threadIdx.x;
  int s = ei[e], dN = ei[EDGES+e];
  int g = (s>>6) - b0, u = s&63, v = dN&63;
  atomicAdd(&cnt[((size_t)g*4096 + v*64 + u)*16 + attr[e]], 1u);
}

// ---------------- expand ----------------
__global__ __launch_bounds__(256) void k_expand(const unsigned int* __restrict__ cnt,
    const float* __restrict__ enc, const float* __restrict__ tt,
    __bf16* __restrict__ A_S, int b0){
  __shared__ float encs[16][128];
  __shared__ float ttl[128];
  __shared__ __bf16 tb[8][256];
  int g = blockIdx.x >> 4;
  int cell0 = (blockIdx.x & 15) << 8;
  int tid = threadIdx.x;
  for (int s = tid; s < 2048; s += 256) encs[s>>7][s&127] = enc[s];
  if (tid < 128) ttl[tid] = tt[(b0+g)*128 + tid];
  unsigned int c16[16];
  { const uint4* src = (const uint4*)(cnt + ((size_t)g*4096 + cell0 + tid)*16);
    uint4 a = src[0], b = src[1], c = src[2], d = src[3];
    c16[0]=a.x; c16[1]=a.y; c16[2]=a.z; c16[3]=a.w;
    c16[4]=b.x; c16[5]=b.y; c16[6]=b.z; c16[7]=b.w;
    c16[8]=c.x; c16[9]=c.y; c16[10]=c.z; c16[11]=c.w;
    c16[12]=d.x; c16[13]=d.y; c16[14]=d.z; c16[15]=d.w; }
  __syncthreads();
  for (int dc=0; dc<16; dc++){
    int d0 = dc*8;
    float vals[8] = {0.f,0.f,0.f,0.f,0.f,0.f,0.f,0.f};
    #pragma unroll
    for (int et=0; et<16; et++){
      unsigned int c = c16[et];
      if (c){
        float fc = (float)c;
        #pragma unroll
        for (int dd=0; dd<8; dd++) vals[dd] = fmaf(fc, encs[et][d0+dd], vals[dd]);
      }
    }
    #pragma unroll
    for (int dd=0; dd<8; dd++) tb[dd][tid] = (__bf16)(vals[dd]*ttl[d0+dd]);
    __syncthreads();
    { int dd = tid>>5, seg = tid&31;
      uint4 v = *(const uint4*)&tb[dd][seg*8];
      *(uint4*)(A_S + ((size_t)(g*128 + d0 + dd)<<12) + cell0 + seg*8) = v; }
    __syncthreads();
  }
}

// ---------------- weight prep: Wt[fo][K] = W^T in bf16 ----------------
__global__ __launch_bounds__(256) void k_wprep(const float* __restrict__ W1, const float* __restrict__ W2,
                                               const float* __restrict__ Wm, __bf16* __restrict__ WT){
  int b = blockIdx.x, t = threadIdx.x;
  const float* src; __bf16* dst; int K;
  if (b < 6){ src = W1 + (size_t)b*384*128; dst = WT + (size_t)b*49152; K = 384; }
  else if (b < 12){ src = W2 + (size_t)(b-6)*128*128; dst = WT + 294912 + (size_t)(b-6)*16384; K = 128; }
  else { src = Wm; dst = WT + 393216; K = 128; }
  __shared__ float L[64][129];
  for (int k0 = 0; k0 < K; k0 += 64){
    __syncthreads();
    int r = t>>2, c = (t&3)*32;
    #pragma unroll
    for (int e=0;e<32;e+=4){
      float4 x = *(const float4*)(src + (size_t)(k0+r)*128 + c + e);
      L[r][c+e]=x.x; L[r][c+e+1]=x.y; L[r][c+e+2]=x.z; L[r][c+e+3]=x.w;
    }
    __syncthreads();
    int fo = t>>1, kk = (t&1)*32;
    union { __bf16 h[32]; uint4 u[4]; } o;
    #pragma unroll
    for (int e=0;e<32;e++) o.h[e] = (__bf16)L[kk+e][fo];
    uint4* d4 = (uint4*)(dst + (size_t)fo*K + k0 + kk);
    d4[0]=o.u[0]; d4[1]=o.u[1]; d4[2]=o.u[2]; d4[3]=o.u[3];
  }
}

// ---------------- fn weight prep ----------------
__global__ __launch_bounds__(256) void k_wprepfn(const float* __restrict__ W1, const float* __restrict__ W2,
                                                 __bf16* __restrict__ o1, __bf16* __restrict__ o2){
  int b = blockIdx.x, t = threadIdx.x;
  const float* src; __bf16* dst; int K, N, k0, n0;
  if (b < 8){ src = W1; dst = o1; K = 128; N = 256; k0 = (b>>2)*64; n0 = (b&3)*64; }
  else { int bb = b-8; src = W2; dst = o2; K = 256; N = 128; k0 = (bb>>1)*64; n0 = (bb&1)*64; }
  __shared__ float L[64][65];
  int r = t>>2, c4 = (t&3)*16;
  #pragma unroll
  for (int e=0;e<16;e+=4){
    float4 x = *(const float4*)(src + (size_t)(k0+r)*N + n0 + c4 + e);
    L[r][c4+e]=x.x; L[r][c4+e+1]=x.y; L[r][c4+e+2]=x.z; L[r][c4+e+3]=x.w;
  }
  __syncthreads();
  int n = t>>2, kc = (t&3)*16;
  union { __bf16 h[16]; uint4 u[2]; } o;
  #pragma unroll
  for (int e=0;e<16;e++) o.h[e] = (__bf16)L[kc+e][n];
  uint4* d4 = (uint4*)(dst + (size_t)(n0+n)*K + k0 + kc);
  d4[0]=o.u[0]; d4[1]=o.u[1];
}

// ---------------- einsum (MFMA): GLL staging; derives transposes; coalesced C-write ----------------
__global__ __launch_bounds__(256) void k_einsum(const __bf16* __restrict__ As,
                                                const __bf16* __restrict__ Xs,
                                                __bf16* __restrict__ X1t, __bf16* __restrict__ X2t){
  __shared__ __bf16 S[8][4096];
  int tid = threadIdx.x;
  int w = tid>>6, lane = tid&63;
  size_t p0 = (size_t)blockIdx.x * 2;
  {
    int slot = (w<2) ? (2+w) : (4+w);
    const __bf16* srcp = ((w<2) ? As : Xs) + (p0 + (w&1))*4096;
    #pragma unroll
    for (int c8 = 0; c8 < 8; c8++){
      int row = c8*8 + (lane>>3);
      int ch  = (lane&7) ^ (row&7);
      gll16(srcp + row*64 + ch*8, (char*)&S[slot][0] + c8*1024);
    }
  }
  __syncthreads();
  {
    int q = tid>>6, v = tid&63;
    int ssl = (q<2) ? (2+q) : (4+q);
    int dsl = (q<2) ? q : (2+q);
    const unsigned char* sb = (const unsigned char*)S[ssl];
    unsigned char* db = (unsigned char*)S[dsl];
    #pragma unroll
    for (int uo=0; uo<8; uo++){
      union { __bf16 h[8]; uint4 u; } pk;
      #pragma unroll
      for (int e=0;e<8;e++){
        int u = uo*8+e;
        pk.h[e] = *(const __bf16*)(sb + u*128 + (((v>>3) ^ (u&7))<<4) + (v&7)*2);
      }
      *(uint4*)(db + v*128 + ((uo ^ (v&7))<<4)) = pk.u;
    }
  }
  __syncthreads();
  int pl = w>>1, pr = w&1;
  const __bf16* M  = pr ? S[4+pl] : S[0+pl];
  const __bf16* Bt = pr ? S[2+pl] : S[6+pl];
  f32x4 acc[4][4];
  #pragma unroll
  for (int a=0;a<4;a++)
    #pragma unroll
    for(int b=0;b<4;b++) acc[a][b] = (f32x4){0.f,0.f,0.f,0.f};
  int lr = lane&15, lq = lane>>4;
  #pragma unroll
  for (int ks=0;ks<2;ks++){
    bf16x8 af[4], bfr[4];
    #pragma unroll
    for (int mt=0;mt<4;mt++){ int r = mt*16+lr; af[mt] = *(const bf16x8*)&M[r*64 + (((ks*4+lq) ^ (r&7))<<3)]; }
    #pragma unroll
    for (int nt=0;nt<4;nt++){ int r = nt*16+lr; bfr[nt] = *(const bf16x8*)&Bt[r*64 + (((ks*4+lq) ^ (r&7))<<3)]; }
    #pragma unroll
    for (int mt=0;mt<4;mt++)
      #pragma unroll
      for (int nt=0;nt<4;nt++)
        acc[mt][nt] = __builtin_amdgcn_mfma_f32_16x16x32_bf16(af[mt], bfr[nt], acc[mt][nt], 0,0,0);
  }
  {
    int dslot = pr ? (4+pl) : pl;
    unsigned char* db = (unsigned char*)&S[dslot][0];
    #pragma unroll
    for (int mt=0;mt<4;mt++)
      #pragma unroll
      for (int nt=0;nt<4;nt++){
        int col = nt*16 + lr; int row0 = mt*16 + lq*4;
        union { __bf16 h[4]; uint2 u; } o;
        #pragma unroll
        for (int r=0;r<4;r++) o.h[r] = (__bf16)acc[mt][nt][r];
        int chunk = row0>>3;
        *(uint2*)(db + col*128 + ((chunk ^ (col&7))<<4) + (row0&7)*2) = o.u;
      }
  }
  __syncthreads();
  #pragma unroll
  for (int s4=0; s4<4; s4++){
    int slot = (s4<2) ? s4 : (2+s4);
    __bf16* dst = ((s4<2) ? X1t : X2t) + (p0 + (s4&1))*4096;
    const unsigned char* sb = (const unsigned char*)&S[slot][0];
    #pragma unroll
    for (int q=0;q<2;q++){
      int t2 = tid + q*256;
      int col = t2>>3, rc = t2&7;
      uint4 v = *(const uint4*)(sb + col*128 + ((rc ^ (col&7))<<4));
      *(uint4*)(dst + t2*8) = v;
    }
  }
}

// ---------------- fused conv1+LN1+relu+conv2+LN2+relu+residual ----------------
// 3-stage pipeline, ONE barrier per K-step (no setprio — T5 hurts this structure).
__global__ __launch_bounds__(256) void k_layer(const __bf16* __restrict__ Xold,
    const __bf16* __restrict__ X1, const __bf16* __restrict__ X2,
    const __bf16* __restrict__ W1t, const __bf16* __restrict__ W2t,
    const float* __restrict__ b1v, const float* __restrict__ g1v, const float* __restrict__ bt1v,
    const float* __restrict__ b2v, const float* __restrict__ g2v, const float* __restrict__ bt2v,
    __bf16* __restrict__ Xnew){
  __shared__ __align__(16) unsigned char RG[32768];
  __shared__ float stats[2][128];
  __bf16* y1T = (__bf16*)RG;
  float (*redS)[128] = (float(*)[128])(RG + 16384);
  float (*redQ)[128] = (float(*)[128])(RG + 18432);
  int tid = threadIdx.x, w = tid>>6, lane = tid&63, lr = lane&15, lq = lane>>4;
  int colTile = blockIdx.x << 7;
  int bl = colTile >> 12;
  int colInB = colTile & 4095;
  int s_fi = tid>>3, s_o = tid&7;
  int r_col = tid>>1;

  f32x4 acc[2][8];
  #pragma unroll
  for (int a=0;a<2;a++)
    #pragma unroll
    for (int b=0;b<8;b++) acc[a][b] = (f32x4){0.f,0.f,0.f,0.f};

#define STAGE(ks, nb) { \
    int gfi = (ks)*32 + s_fi; \
    const __bf16* T = (gfi<128)? Xold : (gfi<256? X1 : X2); \
    int d = gfi & 127; \
    const uint4* src = (const uint4*)(T + ((size_t)(bl*128 + d)<<12) + colInB + s_o*16); \
    uint4 v0 = src[0], v1 = src[1]; \
    unsigned char* Nd = RG + (nb)*8192; \
    *(uint4*)(Nd + s_fi*256 + (((s_o*2+0) ^ (s_fi&15))<<4)) = v0; \
    *(uint4*)(Nd + s_fi*256 + (((s_o*2+1) ^ (s_fi&15))<<4)) = v1; \
  }

#define REPACK(nb) { \
    const unsigned char* Ns = RG + (nb)*8192; \
    unsigned char* Cd = RG + 16384 + (nb)*8192; \
    _Pragma("unroll") \
    for (int j=0;j<2;j++){ \
      int oct = (tid&1)*2 + j; \
      union { __bf16 h[8]; uint4 u; } pk; \
      _Pragma("unroll") \
      for (int e=0;e<8;e++){ \
        int fi = oct*8 + e; \
        pk.h[e] = *(const __bf16*)(Ns + fi*256 + (((r_col>>3) ^ (fi&15))<<4) + (r_col&7)*2); \
      } \
      *(uint4*)(Cd + r_col*64 + ((oct ^ (r_col&3))<<4)) = pk.u; \
    } \
  }

  STAGE(0, 0)
  STAGE(1, 1)
  __syncthreads();
  REPACK(0)
  __syncthreads();

  for (int k=0; k<11; k++){
    int cb = k&1, nb = cb^1;
    const unsigned char* Cc = RG + 16384 + cb*8192;
    bf16x8 af[2];
    #pragma unroll
    for (int mt=0;mt<2;mt++){
      int fo = w*32 + mt*16 + lr;
      af[mt] = *(const bf16x8*)(W1t + (size_t)fo*384 + k*32 + lq*8);
    }
    bf16x8 bfr[8];
    #pragma unroll
    for (int nt=0;nt<8;nt++){ int cr = nt*16+lr; bfr[nt] = *(const bf16x8*)(Cc + cr*64 + ((lq ^ (cr&3))<<4)); }
    #pragma unroll
    for (int mt=0;mt<2;mt++)
      #pragma unroll
      for (int nt=0;nt<8;nt++)
        acc[mt][nt] = __builtin_amdgcn_mfma_f32_16x16x32_bf16(af[mt], bfr[nt], acc[mt][nt], 0,0,0);
    REPACK(nb)
    if (k < 10) STAGE(k+2, cb)
    __syncthreads();
  }
  {
    const unsigned char* Cc = RG + 16384 + 8192;
    bf16x8 af[2];
    #pragma unroll
    for (int mt=0;mt<2;mt++){
      int fo = w*32 + mt*16 + lr;
      af[mt] = *(const bf16x8*)(W1t + (size_t)fo*384 + 11*32 + lq*8);
    }
    bf16x8 bfr[8];
    #pragma unroll
    for (int nt=0;nt<8;nt++){ int cr = nt*16+lr; bfr[nt] = *(const bf16x8*)(Cc + cr*64 + ((lq ^ (cr&3))<<4)); }
    #pragma unroll
    for (int mt=0;mt<2;mt++)
      #pragma unroll
      for (int nt=0;nt<8;nt++)
        acc[mt][nt] = __builtin_amdgcn_mfma_f32_16x16x32_bf16(af[mt], bfr[nt], acc[mt][nt], 0,0,0);
  }

  #pragma unroll
  for (int mt=0;mt<2;mt++){
    #pragma unroll
    for (int r=0;r<4;r++){
      float bv = b1v[w*32 + mt*16 + lq*4 + r];
      #pragma unroll
      for (int nt=0;nt<8;nt++) acc[mt][nt][r] += bv;
    }
  }
  {
    float cs[8], cq[8];
    #pragma unroll
    for (int nt=0;nt<8;nt++){ cs[nt]=0.f; cq[nt]=0.f; }
    #pragma unroll
    for (int mt=0;mt<2;mt++)
      #pragma unroll
      for (int nt=0;nt<8;nt++)
        #pragma unroll
        for (int r=0;r<4;r++){ float v = acc[mt][nt][r]; cs[nt] += v; cq[nt] = fmaf(v,v,cq[nt]); }
    #pragma unroll
    for (int nt=0;nt<8;nt++){
      cs[nt] += __shfl_xor(cs[nt], 16); cq[nt] += __shfl_xor(cq[nt], 16);
      cs[nt] += __shfl_xor(cs[nt], 32); cq[nt] += __shfl_xor(cq[nt], 32);
    }
    if (lq == 0){
      #pragma unroll
      for (int nt=0;nt<8;nt++){ redS[w][nt*16+lr] = cs[nt]; redQ[w][nt*16+lr] = cq[nt]; }
    }
  }
  __syncthreads();
  if (tid < 128){
    float S = redS[0][tid]+redS[1][tid]+redS[2][tid]+redS[3][tid];
    float Q = redQ[0][tid]+redQ[1][tid]+redQ[2][tid]+redQ[3][tid];
    float m = S*(1.f/128.f);
    float var = Q*(1.f/128.f) - m*m;
    stats[0][tid] = m; stats[1][tid] = rsqrtf(var + 1e-5f);
  }
  __syncthreads();
  #pragma unroll
  for (int mt=0;mt<2;mt++){
    int fo1b = w*32 + mt*16 + lq*4;
    float ga[4], be[4];
    #pragma unroll
    for (int r=0;r<4;r++){ ga[r] = g1v[fo1b+r]; be[r] = bt1v[fo1b+r]; }
    #pragma unroll
    for (int nt=0;nt<8;nt++){
      int col = nt*16 + lr;
      union { __bf16 h[4]; uint2 u; } o;
      #pragma unroll
      for (int r=0;r<4;r++){
        float xx = (acc[mt][nt][r] - stats[0][col]) * stats[1][col] * ga[r] + be[r];
        o.h[r] = (__bf16)fmaxf(xx, 0.f);
      }
      *(uint2*)&y1T[col*128 + (fo1b ^ ((col&15)<<3))] = o.u;
    }
  }
  __syncthreads();

  f32x4 acc2[2][8];
  #pragma unroll
  for (int a=0;a<2;a++)
    #pragma unroll
    for (int b=0;b<8;b++) acc2[a][b] = (f32x4){0.f,0.f,0.f,0.f};
  #pragma unroll
  for (int ks2=0; ks2<4; ks2++){
    bf16x8 af[2], bfr[8];
    #pragma unroll
    for (int mt=0;mt<2;mt++){
      int fo = w*32 + mt*16 + lr;
      af[mt] = *(const bf16x8*)(W2t + (size_t)fo*128 + ks2*32 + lq*8);
    }
    #pragma unroll
    for (int nt=0;nt<8;nt++){ int cr = nt*16+lr; bfr[nt] = *(const bf16x8*)&y1T[cr*128 + ((ks2*32 + lq*8) ^ ((cr&15)<<3))]; }
    #pragma unroll
    for (int mt=0;mt<2;mt++)
      #pragma unroll
      for (int nt=0;nt<8;nt++)
        acc2[mt][nt] = __builtin_amdgcn_mfma_f32_16x16x32_bf16(af[mt], bfr[nt], acc2[mt][nt], 0,0,0);
  }
  __syncthreads();

  #pragma unroll
  for (int mt=0;mt<2;mt++){
    #pragma unroll
    for (int r=0;r<4;r++){
      float bv = b2v[w*32 + mt*16 + lq*4 + r];
      #pragma unroll
      for (int nt=0;nt<8;nt++) acc2[mt][nt][r] += bv;
    }
  }
  {
    float cs[8], cq[8];
    #pragma unroll
    for (int nt=0;nt<8;nt++){ cs[nt]=0.f; cq[nt]=0.f; }
    #pragma unroll
    for (int mt=0;mt<2;mt++)
      #pragma unroll
      for (int nt=0;nt<8;nt++)
        #pragma unroll
        for (int r=0;r<4;r++){ float v = acc2[mt][nt][r]; cs[nt] += v; cq[nt] = fmaf(v,v,cq[nt]); }
    #pragma unroll
    for (int nt=0;nt<8;nt++){
      cs[nt] += __shfl_xor(cs[nt], 16); cq[nt] += __shfl_xor(cq[nt], 16);
      cs[nt] += __shfl_xor(cs[nt], 32); cq[nt] += __shfl_xor(cq[nt], 32);
    }
    if (lq == 0){
      #pragma unroll
      for (int nt=0;nt<8;nt++){ redS[w][nt*16+lr] = cs[nt]; redQ[w][nt*16+lr] = cq[nt]; }
    }
  }
  __syncthreads();
  if (tid < 128){
    float S = redS[0][tid]+redS[1][tid]+redS[2][tid]+redS[3][tid];
    float Q = redQ[0][tid]+redQ[1][tid]+redQ[2][tid]+redQ[3][tid];
    float m = S*(1.f/128.f);
    float var = Q*(1.f/128.f) - m*m;
    stats[0][tid] = m; stats[1][tid] = rsqrtf(var + 1e-5f);
  }
  __syncthreads();
  #pragma unroll
  for (int mt=0;mt<2;mt++){
    #pragma unroll
    for (int r=0;r<4;r++){
      int fo = w*32 + mt*16 + lq*4 + r;
      float ga = g2v[fo], be = bt2v[fo];
      size_t rowb = ((size_t)(bl*128 + fo)<<12) + colInB;
      #pragma unroll
      for (int nt=0;nt<8;nt++){
        int cp = nt*16 + lr;
        float xx = (acc2[mt][nt][r] - stats[0][cp]) * stats[1][cp] * ga + be;
        float o = fmaxf(xx, 0.f);
        float old = (float)Xold[rowb + cp];
        Xnew[rowb + cp] = (__bf16)(o + old);
      }
    }
  }
#undef STAGE
#undef REPACK
}

// ---------------- to node-major (unsymmetrized): NM0[g*4096+cell][d] = X_S[g*128+d][cell] ----------------
__global__ __launch_bounds__(256) void k_tonm(const __bf16* __restrict__ S, __bf16* __restrict__ NM){
  __shared__ unsigned short L[64][65];
  int b = blockIdx.x;
  int g = b >> 7, dh = (b>>6)&1, cc = b&63;
  int cell0 = cc*64, d0 = dh*64;
  int tid = threadIdx.x;
  int r = tid>>2, c = (tid&3)*16;
  union { unsigned short h[16]; uint4 u[2]; } in;
  const unsigned short* src = (const unsigned short*)S + ((size_t)(g*128 + d0 + r)<<12) + cell0 + c;
  in.u[0] = *(const uint4*)src;
  in.u[1] = *(const uint4*)(src + 8);
  #pragma unroll
  for (int e=0;e<16;e++) L[r][c+e] = in.h[e];
  __syncthreads();
  union { unsigned short h[16]; uint4 u[2]; } o;
  int cr = tid>>2, dc = (tid&3)*16;
  #pragma unroll
  for (int e=0;e<16;e++) o.h[e] = L[dc+e][cr];
  unsigned short* dst = (unsigned short*)NM + (size_t)(g*4096 + cell0 + cr)*128 + d0 + dc;
  *(uint4*)dst       = o.u[0];
  *(uint4*)(dst + 8) = o.u[1];
}

// ---------------- mlp hidden from cell-major; symmetrize on the fly ----------------
__global__ __launch_bounds__(256) void k_mlph(const __bf16* __restrict__ NM,
    const __bf16* __restrict__ Wt, const float* __restrict__ bias, __bf16* __restrict__ hid){
  __shared__ __align__(16) unsigned char WcB[8192];
  __shared__ __align__(16) unsigned char EcB[8192];
  __bf16* Wc = (__bf16*)WcB;
  unsigned char* Ec = EcB;
  int tid = threadIdx.x, w = tid>>6, lane = tid&63, lr = lane&15, lq = lane>>4;
  int g = blockIdx.x >> 5;
  int cellloc0 = (blockIdx.x & 31) << 7;
  size_t cellbase = ((size_t)g<<12) + cellloc0;
  int mh = w&1, nh = w>>1;
  f32x4 acc[4][4];
  #pragma unroll
  for (int a=0;a<4;a++)
    #pragma unroll
    for (int b=0;b<4;b++) acc[a][b] = (f32x4){0.f,0.f,0.f,0.f};
  for (int ks=0; ks<4; ks++){
    __syncthreads();
    { int fo = tid>>1, half = tid&1;
      const uint4* src = (const uint4*)(Wt + (size_t)fo*128 + ks*32 + half*16);
      uint4 v0 = src[0], v1 = src[1];
      *(uint4*)&Wc[fo*32 + (((half*2+0) ^ (fo&3))<<3)] = v0;
      *(uint4*)&Wc[fo*32 + (((half*2+1) ^ (fo&3))<<3)] = v1;
    }
    { int cell = tid>>1, half = tid&1;
      int cl = cellloc0 + cell;
      int v = cl>>6, u = cl&63;
      size_t cT = ((size_t)g<<12) + u*64 + v;
      const uint4* src  = (const uint4*)(NM + (cellbase + cell)*128 + ks*32 + half*16);
      const uint4* srcT = (const uint4*)(NM + cT*128 + ks*32 + half*16);
      uint4 v0 = addbf8(src[0], srcT[0]);
      uint4 v1 = addbf8(src[1], srcT[1]);
      *(uint4*)(Ec + cell*64 + (((half*2+0) ^ (cell&3))<<4)) = v0;
      *(uint4*)(Ec + cell*64 + (((half*2+1) ^ (cell&3))<<4)) = v1;
    }
    __syncthreads();
    bf16x8 af[4], bfr[4];
    #pragma unroll
    for (int mt=0;mt<4;mt++){ int cr = mh*64 + mt*16 + lr; af[mt] = *(const bf16x8*)(Ec + cr*64 + ((lq ^ (cr&3))<<4)); }
    #pragma unroll
    for (int nt=0;nt<4;nt++){ int fo = nh*64 + nt*16 + lr; bfr[nt] = *(const bf16x8*)&Wc[fo*32 + ((lq ^ (fo&3))<<3)]; }
    #pragma unroll
    for (int mt=0;mt<4;mt++)
      #pragma unroll
      for (int nt=0;nt<4;nt++)
        acc[mt][nt] = __builtin_amdgcn_mfma_f32_16x16x32_bf16(af[mt], bfr[nt], acc[mt][nt], 0,0,0);
  }
  #pragma unroll
  for (int mt=0;mt<4;mt++)
    #pragma unroll
    for (int r=0;r<4;r++){
      size_t cell = cellbase + mh*64 + mt*16 + lq*4 + r;
      #pragma unroll
      for (int nt=0;nt<4;nt++){
        int fo = nh*64 + nt*16 + lr;
        hid[cell*128 + fo] = (__bf16)silu_f(acc[mt][nt][r] + bias[fo]);
      }
    }
}

// ---------------- ym ----------------
__global__ void k_ymean(const __bf16* __restrict__ hid, float* __restrict__ ym){
  __shared__ float red[256];
  int g = blockIdx.x >> 6, u = blockIdx.x & 63;
  int fo = threadIdx.x & 127, vh = threadIdx.x >> 7;
  const unsigned short* hu = (const unsigned short*)hid;
  float s = 0.f;
  for (int v = vh; v < 64; v += 2)
    s += bf2f(hu[((size_t)g*4096 + v*64 + u)*128 + fo]);
  red[threadIdx.x] = s;
  __syncthreads();
  if (vh == 0) ym[((size_t)g*64 + u)*128 + fo] = (red[fo] + red[128+fo]) * (1.f/64.f);
}

// ---------------- h2 ----------------
__global__ void k_h2(const float* __restrict__ ym, const float* __restrict__ W2,
                     const float* __restrict__ b2, float* __restrict__ h2){
  int row = blockIdx.x, fo = threadIdx.x;
  __shared__ float rr[128];
  rr[fo] = ym[(size_t)row*128 + fo];
  __syncthreads();
  float a = b2[fo];
  #pragma unroll 4
  for (int k=0;k<128;k++) a = fmaf(rr[k], W2[k*128+fo], a);
  h2[(size_t)row*128+fo] = a;
}

// ---------------- final MLP (MFMA); GATHER path symmetrizes (cell + cellT) ----------------
template<int GATHER>
__global__ __launch_bounds__(256) void k_fmlp(const __bf16* __restrict__ NM, const float* __restrict__ RWS,
    const int* __restrict__ ei,
    const __bf16* __restrict__ W1t, const float* __restrict__ b1,
    const __bf16* __restrict__ W2t, const float* __restrict__ b2,
    float* __restrict__ outp, int b0){
  __shared__ __align__(16) unsigned char RA[32768];
  __shared__ __align__(16) unsigned char RB[8192];
  __shared__ int cells[64];
  __shared__ int cellsT[64];
  __bf16* eo  = (__bf16*)RA;
  __bf16* Wc  = (__bf16*)(RA + 16384);
  __bf16* hid = (__bf16*)RA;
  __bf16* W2c = (__bf16*)RB;
  int tid = threadIdx.x, w = tid>>6, lane = tid&63, lr = lane&15, lq = lane>>4;
  int r0 = blockIdx.x*64;
  if (GATHER){
    if (tid < 64){
      int e = b0*512 + r0 + tid;
      int s = ei[e], dN = ei[EDGES+e];
      int g = (s>>6) - b0, u = s&63, v = dN&63;
      cells[tid]  = g*4096 + v*64 + u;
      cellsT[tid] = g*4096 + u*64 + v;
    }
    __syncthreads();
  }
  { int el = tid>>2, o4 = tid&3;
    if (GATHER){
      const unsigned short* src  = (const unsigned short*)NM + (size_t)cells[el]*128;
      const unsigned short* srcT = (const unsigned short*)NM + (size_t)cellsT[el]*128;
      #pragma unroll
      for (int j=0;j<4;j++){
        int ch = o4*4 + j;
        uint4 v = addbf8(*(const uint4*)(src + ch*8), *(const uint4*)(srcT + ch*8));
        *(uint4*)&eo[el*128 + ((ch*8) ^ ((el&15)*8))] = v;
      }
    } else {
      const float* src = RWS + (size_t)(r0 + el)*128;
      #pragma unroll
      for (int j=0;j<4;j++){
        int ch = o4*4 + j;
        union { __bf16 h[8]; uint4 u; } pk;
        #pragma unroll
        for (int e2=0;e2<8;e2++) pk.h[e2] = (__bf16)src[ch*8 + e2];
        *(uint4*)&eo[el*128 + ((ch*8) ^ ((el&15)*8))] = pk.u;
      }
    }
  }
  f32x4 acc[4][4];
  #pragma unroll
  for (int a=0;a<4;a++)
    #pragma unroll
    for (int b=0;b<4;b++) acc[a][b] = (f32x4){0.f,0.f,0.f,0.f};
  for (int ks=0; ks<4; ks++){
    if (ks) __syncthreads();
    { int fo = tid;
      const uint4* src = (const uint4*)(W1t + (size_t)fo*128 + ks*32);
      #pragma unroll
      for (int o=0;o<4;o++){
        uint4 v = src[o];
        *(uint4*)&Wc[fo*32 + ((o ^ (fo&3))<<3)] = v;
      }
    }
    __syncthreads();
    bf16x8 af[4], bfr[4];
    #pragma unroll
    for (int mt=0;mt<4;mt++){ int fo = w*64+mt*16+lr; af[mt] = *(const bf16x8*)&Wc[fo*32 + ((lq ^ (fo&3))<<3)]; }
    #pragma unroll
    for (int nt=0;nt<4;nt++){ int ed = nt*16+lr; bfr[nt] = *(const bf16x8*)&eo[ed*128 + ((ks*32+lq*8) ^ ((ed&15)*8))]; }
    #pragma unroll
    for (int mt=0;mt<4;mt++)
      #pragma unroll
      for (int nt=0;nt<4;nt++)
        acc[mt][nt] = __builtin_amdgcn_mfma_f32_16x16x32_bf16(af[mt], bfr[nt], acc[mt][nt], 0,0,0);
  }
  __syncthreads();
  #pragma unroll
  for (int mt=0;mt<4;mt++){
    int fob = w*64 + mt*16 + lq*4;
    float bv[4];
    #pragma unroll
    for (int r=0;r<4;r++) bv[r] = b1[fob+r];
    #pragma unroll
    for (int nt=0;nt<4;nt++){
      int ed = nt*16 + lr;
      union { __bf16 h[4]; uint2 u; } o;
      #pragma unroll
      for (int r=0;r<4;r++) o.h[r] = (__bf16)fmaxf(acc[mt][nt][r] + bv[r], 0.f);
      *(uint2*)&hid[ed*256 + (fob ^ ((ed&31)*8))] = o.u;
    }
  }
  f32x4 acc2[4][2];
  #pragma unroll
  for (int a=0;a<4;a++)
    #pragma unroll
    for (int b=0;b<2;b++) acc2[a][b] = (f32x4){0.f,0.f,0.f,0.f};
  int mh = w&1, nh = w>>1;
  for (int ks2=0; ks2<8; ks2++){
    __syncthreads();
    { int fo = tid>>1, half = tid&1;
      const uint4* src = (const uint4*)(W2t + (size_t)fo*256 + ks2*32 + half*16);
      uint4 v0 = src[0], v1 = src[1];
      *(uint4*)&W2c[fo*32 + (((half*2+0) ^ (fo&3))<<3)] = v0;
      *(uint4*)&W2c[fo*32 + (((half*2+1) ^ (fo&3))<<3)] = v1;
    }
    __syncthreads();
    bf16x8 af2[4], bfr2[2];
    #pragma unroll
    for (int mt=0;mt<4;mt++){ int fo2 = mh*64+mt*16+lr; af2[mt] = *(const bf16x8*)&W2c[fo2*32 + ((lq ^ (fo2&3))<<3)]; }
    #pragma unroll
    for (int nt=0;nt<2;nt++){ int ed = nh*32+nt*16+lr; bfr2[nt] = *(const bf16x8*)&hid[ed*256 + ((ks2*32+lq*8) ^ ((ed&31)*8))]; }
    #pragma unroll
    for (int mt=0;mt<4;mt++)
      #pragma unroll
      for (int nt=0;nt<2;nt++)
        acc2[mt][nt] = __builtin_amdgcn_mfma_f32_16x16x32_bf16(af2[mt], bfr2[nt], acc2[mt][nt], 0,0,0);
  }
  #pragma unroll
  for (int mt=0;mt<4;mt++){
    int fo2b = mh*64 + mt*16 + lq*4;
    float bv[4];
    #pragma unroll
    for (int r=0;r<4;r++) bv[r] = b2[fo2b+r];
    #pragma unroll
    for (int nt=0;nt<2;nt++){
      int ed = nh*32 + nt*16 + lr;
      float4 o = make_float4(acc2[mt][nt][0]+bv[0], acc2[mt][nt][1]+bv[1],
                             acc2[mt][nt][2]+bv[2], acc2[mt][nt][3]+bv[3]);
      *(float4*)(outp + (size_t)(r0 + ed)*128 + fo2b) = o;
    }
  }
}

// ---------------- graph_attr ----------------
__global__ void k_graph(const float* __restrict__ node_out, float* __restrict__ gout){
  int b = blockIdx.x, d = threadIdx.x;
  float s = 0.f;
  for (int i=0;i<64;i++) s += node_out[(size_t)(b*64+i)*128 + d];
  gout[b*128 + d] = s * (1.f/64.f);
}

extern "C" void kernel_launch(void* const* d_in, const int* in_sizes, int n_in,
                              void* d_out, int out_size, void* d_ws, size_t ws_size,
                              hipStream_t stream) {
  const int*   edge_index = (const int*)d_in[1];
  const int*   edge_attr  = (const int*)d_in[2];
  const float* t        = (const float*)d_in[3];
  const float* edge_emb = (const float*)d_in[5];
  const float* temb_W1  = (const float*)d_in[6];
  const float* temb_b1  = (const float*)d_in[7];
  const float* temb_W2  = (const float*)d_in[8];
  const float* temb_b2  = (const float*)d_in[9];
  const float* ein_W1   = (const float*)d_in[14];
  const float* ein_b1   = (const float*)d_in[15];
  const float* ein_W2   = (const float*)d_in[16];
  const float* ein_b2   = (const float*)d_in[17];
  const float* conv_W1  = (const float*)d_in[18];
  const float* conv_b1  = (const float*)d_in[19];
  const float* conv_g1  = (const float*)d_in[20];
  const float* conv_bt1 = (const float*)d_in[21];
  const float* conv_W2  = (const float*)d_in[22];
  const float* conv_b2  = (const float*)d_in[23];
  const float* conv_g2  = (const float*)d_in[24];
  const float* conv_bt2 = (const float*)d_in[25];
  const float* mlp_W1   = (const float*)d_in[26];
  const float* mlp_b1   = (const float*)d_in[27];
  const float* mlp_W2   = (const float*)d_in[28];
  const float* mlp_b2   = (const float*)d_in[29];
  const float* fn_W1    = (const float*)d_in[30];
  const float* fn_b1    = (const float*)d_in[31];
  const float* fn_W2    = (const float*)d_in[32];
  const float* fn_b2    = (const float*)d_in[33];

  float* ws  = (float*)d_ws;
  float* tt  = ws;
  float* enc = ws + 4096;
  float* ym  = ws + 6144;
  float* h2  = ws + 268288;
  __bf16* WT = (__bf16*)(ws + 530432);
  unsigned int* cnt = (unsigned int*)(ws + 768000);
  const size_t HDRF = 2883584;

  __bf16* fnW1t = WT + 409600;
  __bf16* fnW2t = WT + 442368;

  size_t availF = ws_size / sizeof(float);
  const int cands[6] = {32, 16, 8, 4, 2, 1};
  int C = 1;
  for (int i = 0; i < 6; i++){
    if (HDRF + 4ull * (size_t)cands[i] * 262144ull <= availF){ C = cands[i]; break; }
  }
  const size_t PCB = (size_t)C * 262144;
  __bf16* A_S = (__bf16*)(ws + HDRF);
  __bf16* X_S = (__bf16*)(ws + HDRF + PCB);
  __bf16* X1  = (__bf16*)(ws + HDRF + 2*PCB);
  __bf16* X2  = (__bf16*)(ws + HDRF + 3*PCB);
  float* outf = (float*)d_out;

  k_temb<<<NB, DD, 0, stream>>>(t, temb_W1, temb_b1, temb_W2, temb_b2, tt);
  k_edgeenc<<<16, 256, 0, stream>>>(edge_emb, ein_W1, ein_b1, ein_W2, ein_b2, enc);
  k_wprep<<<13, 256, 0, stream>>>(conv_W1, conv_W2, mlp_W1, WT);
  k_wprepfn<<<16, 256, 0, stream>>>(fn_W1, fn_W2, fnW1t, fnW2t);

  for (int b0 = 0; b0 < NB; b0 += C){
    hipMemsetAsync(cnt, 0, (size_t)C*4096*16*sizeof(unsigned int), stream);
    k_cnt<<<C*2, 256, 0, stream>>>(edge_index, edge_attr, cnt, b0);
    k_expand<<<C*16, 256, 0, stream>>>(cnt, enc, tt, A_S, b0);

    for (int l=0; l<LAYERS; l++){
      const __bf16* Xs_l = (l==0) ? A_S : X_S;
      k_einsum<<<C*64, 256, 0, stream>>>(A_S, Xs_l, X1, X2);
      k_layer<<<C*32, 256, 0, stream>>>(Xs_l, X1, X2,
          WT + (size_t)l*49152, WT + 294912 + (size_t)l*16384,
          conv_b1 + l*DD, conv_g1 + l*DD, conv_bt1 + l*DD,
          conv_b2 + l*DD, conv_g2 + l*DD, conv_bt2 + l*DD, X_S);
    }

    k_tonm<<<C*128, 256, 0, stream>>>(X_S, X1);
    k_mlph<<<C*32, 256, 0, stream>>>(X1, WT + 393216, mlp_b1, X2);
    k_ymean<<<C*64, 256, 0, stream>>>(X2, ym);
    k_h2<<<C*64, 128, 0, stream>>>(ym, mlp_W2, mlp_b2, h2);
    k_fmlp<1><<<C*8, 256, 0, stream>>>(X1, nullptr, edge_index, fnW1t, fn_b1, fnW2t, fn_b2,
                                       outf + 262144 + (size_t)b0*512*128, b0);
    k_fmlp<0><<<C, 256, 0, stream>>>(nullptr, h2, nullptr, fnW1t, fn_b1, fnW2t, fn_b2,
                                     outf + (size_t)b0*64*128, b0);
    k_graph<<<C, DD, 0, stream>>>(outf + (size_t)b0*64*DD, outf + 2359296 + b0*DD);
  }
}